// Round 1
// baseline (479.910 us; speedup 1.0000x reference)
//
#include <hip/hip_runtime.h>
#include <stdint.h>

#define B_  8
#define SQ_ 2048
#define SK_ 2048
#define D_  512

typedef unsigned short ushort_t;
typedef __attribute__((ext_vector_type(8))) short          short8;
typedef __attribute__((ext_vector_type(8))) unsigned short ushort8;
typedef __attribute__((ext_vector_type(4))) float          f32x4;

__device__ __forceinline__ unsigned short f2bf(float x) {
  union { float f; unsigned u; } v; v.f = x;
  unsigned r = v.u + 0x7FFFu + ((v.u >> 16) & 1u);   // RNE, finite inputs only
  return (unsigned short)(r >> 16);
}

// async global->LDS, 16B per lane. LDS dest is wave-uniform base + lane*16.
__device__ __forceinline__ void gload_lds16(const void* g, void* l) {
  __builtin_amdgcn_global_load_lds(
      (__attribute__((address_space(1))) void*)(uintptr_t)g,
      (__attribute__((address_space(3))) void*)l, 16, 0, 0);
}

// ---------------- prep: Q,K f32 -> bf16 + row sum-of-squares ----------------
__global__ void prep_qk(const float* __restrict__ Q, const float* __restrict__ K,
                        ushort_t* __restrict__ Qb, ushort_t* __restrict__ Kb,
                        float* __restrict__ q2, float* __restrict__ k2) {
  const int t = threadIdx.x;
  const int rloc = t >> 7;                 // 0/1: which of the 2 rows
  const int row  = blockIdx.x * 2 + rloc;  // 0..32767 (Q rows then K rows)
  const bool isK = row >= B_ * SQ_;
  const int r = isK ? row - B_ * SQ_ : row;
  const float*    src = (isK ? K : Q) + (size_t)r * D_;
  ushort_t*       dst = (isK ? Kb : Qb) + (size_t)r * D_;
  float*          d2  = isK ? k2 : q2;

  const int c = (t & 127) * 4;
  float4 v = *(const float4*)(src + c);
  ushort4 o;
  o.x = f2bf(v.x); o.y = f2bf(v.y); o.z = f2bf(v.z); o.w = f2bf(v.w);
  *(ushort4*)(dst + c) = o;

  float s = v.x * v.x + v.y * v.y + v.z * v.z + v.w * v.w;
  for (int off = 32; off; off >>= 1) s += __shfl_down(s, off);
  __shared__ float ps[4];
  if ((t & 63) == 0) ps[t >> 6] = s;
  __syncthreads();
  if ((t & 127) == 0) d2[r] = ps[rloc * 2] + ps[rloc * 2 + 1];
}

// ---------------- prep: V [B][SK][D] f32 -> VT [B][D][SK] bf16 ----------------
__global__ void prep_vt(const float* __restrict__ V, ushort_t* __restrict__ VT) {
  const int b  = blockIdx.z;
  const int k0 = blockIdx.x * 64;
  const int d0 = blockIdx.y * 64;
  __shared__ __align__(16) ushort_t tile[64][68];
  const int t = threadIdx.x;
  const float* src = V + (size_t)b * SK_ * D_;
  #pragma unroll
  for (int i = 0; i < 4; ++i) {
    int kl = (t >> 4) + i * 16;
    int dl = (t & 15) * 4;
    float4 v = *(const float4*)(src + (size_t)(k0 + kl) * D_ + d0 + dl);
    tile[kl][dl]     = f2bf(v.x);
    tile[kl][dl + 1] = f2bf(v.y);
    tile[kl][dl + 2] = f2bf(v.z);
    tile[kl][dl + 3] = f2bf(v.w);
  }
  __syncthreads();
  ushort_t* dstb = VT + (size_t)b * D_ * SK_;
  #pragma unroll
  for (int j = 0; j < 2; ++j) {
    int chunk = t + j * 256;
    int dl = chunk >> 3;
    int kc = (chunk & 7) << 3;
    ushort8 o;
    #pragma unroll
    for (int m = 0; m < 8; ++m) o[m] = tile[kc + m][dl];
    *(ushort8*)(dstb + (size_t)(d0 + dl) * SK_ + k0 + kc) = o;
  }
}

// ---------------- QK^T + gaussian-kernel epilogue ----------------
// E (unnormalized exp(kernel)) -> W region of d_out; rowsum atomics -> ws.
__global__ __launch_bounds__(256) void qk_kernel(
    const ushort_t* __restrict__ Qb, const ushort_t* __restrict__ Kb,
    const float* __restrict__ q2, const float* __restrict__ k2,
    const float* __restrict__ alphap,
    float* __restrict__ W, float* __restrict__ rowsum) {
  __shared__ __align__(16) ushort_t As[8192];   // 128 x 64 bf16 (swizzled)
  __shared__ __align__(16) ushort_t Bs[8192];
  __shared__ float q2s[128], k2s[128];

  const int t = threadIdx.x;
  const int lane = t & 63, wid = t >> 6;
  const int wm = wid >> 1, wn = wid & 1;
  const int bx = blockIdx.x, by = blockIdx.y, bz = blockIdx.z;

  const ushort_t* Aq = Qb + ((size_t)bz * SQ_ + by * 128) * D_;
  const ushort_t* Bk = Kb + ((size_t)bz * SK_ + bx * 128) * D_;

  if (t < 128) q2s[t] = q2[bz * SQ_ + by * 128 + t];
  else         k2s[t - 128] = k2[bz * SK_ + bx * 128 + (t - 128)];

  f32x4 acc[4][4] = {};
  for (int kt = 0; kt < D_ / 64; ++kt) {
    __syncthreads();
    #pragma unroll
    for (int i = 0; i < 4; ++i) {
      int s = t + i * 256;                 // 16B slot id, 1024 slots per tile
      int row = s >> 3;
      int c16 = (s & 7) ^ (row & 7);       // pre-swizzled global source column
      gload_lds16(Aq + (size_t)row * D_ + kt * 64 + c16 * 8, (char*)As + s * 16);
      gload_lds16(Bk + (size_t)row * D_ + kt * 64 + c16 * 8, (char*)Bs + s * 16);
    }
    __syncthreads();
    #pragma unroll
    for (int kk = 0; kk < 2; ++kk) {
      short8 a[4], bf[4];
      #pragma unroll
      for (int mi = 0; mi < 4; ++mi) {
        int row = (wm << 6) + (mi << 4) + (lane & 15);
        int c = ((kk << 2) + (lane >> 4)) ^ (row & 7);
        a[mi] = *(const short8*)((const char*)As + row * 128 + c * 16);
      }
      #pragma unroll
      for (int ni = 0; ni < 4; ++ni) {
        int col = (wn << 6) + (ni << 4) + (lane & 15);
        int c = ((kk << 2) + (lane >> 4)) ^ (col & 7);
        bf[ni] = *(const short8*)((const char*)Bs + col * 128 + c * 16);
      }
      #pragma unroll
      for (int mi = 0; mi < 4; ++mi)
        #pragma unroll
        for (int ni = 0; ni < 4; ++ni)
          acc[mi][ni] = __builtin_amdgcn_mfma_f32_16x16x32_bf16(a[mi], bf[ni], acc[mi][ni], 0, 0, 0);
    }
  }

  const float alpha = *alphap;
  float* Wb = W + (size_t)bz * SQ_ * SK_;
  const int r0 = (lane >> 4) << 2;
  const int cl = lane & 15;

  float k2c[4];
  #pragma unroll
  for (int ni = 0; ni < 4; ++ni) k2c[ni] = k2s[(wn << 6) + (ni << 4) + cl];

  #pragma unroll
  for (int mi = 0; mi < 4; ++mi) {
    float q2r[4];
    #pragma unroll
    for (int r = 0; r < 4; ++r) q2r[r] = q2s[(wm << 6) + (mi << 4) + r0 + r];
    float se[4] = {0.f, 0.f, 0.f, 0.f};
    #pragma unroll
    for (int ni = 0; ni < 4; ++ni) {
      int gcol = bx * 128 + (wn << 6) + (ni << 4) + cl;
      #pragma unroll
      for (int r = 0; r < 4; ++r) {
        int rl = (wm << 6) + (mi << 4) + r0 + r;
        float sq = fmaxf(q2r[r] + k2c[ni] - 2.0f * acc[mi][ni][r], 0.0f);
        float kv = expf(-alpha * sq);      // the gaussian "kernel" value, in [0,1]
        float e  = expf(kv);               // softmax numerator (no max needed)
        Wb[(size_t)(by * 128 + rl) * SK_ + gcol] = e;
        se[r] += e;
      }
    }
    #pragma unroll
    for (int r = 0; r < 4; ++r) {
      float s = se[r];
      for (int off = 1; off < 16; off <<= 1) s += __shfl_xor(s, off);
      if (cl == 0)
        atomicAdd(&rowsum[bz * SQ_ + by * 128 + (wm << 6) + (mi << 4) + r0 + r], s);
    }
  }
}

// ---------------- PV: out = E * V / rowsum ----------------
__global__ __launch_bounds__(256) void pv_kernel(
    const float* __restrict__ E, const ushort_t* __restrict__ VT,
    const float* __restrict__ rowsum, float* __restrict__ Out) {
  __shared__ __align__(16) ushort_t As[8192];   // E tile 128q x 64k bf16 (swizzled)
  __shared__ __align__(16) ushort_t Bs[8192];   // VT tile 128d x 64k bf16 (swizzled)
  __shared__ float rss[128];

  const int t = threadIdx.x;
  const int lane = t & 63, wid = t >> 6;
  const int wm = wid >> 1, wn = wid & 1;
  const int bx = blockIdx.x;   // d tile (0..3)
  const int by = blockIdx.y;   // q tile (0..15)
  const int bz = blockIdx.z;

  const float*    Eb = E + ((size_t)bz * SQ_ + by * 128) * SK_;
  const ushort_t* Vb = VT + ((size_t)bz * D_ + bx * 128) * SK_;

  if (t < 128) rss[t] = rowsum[bz * SQ_ + by * 128 + t];

  f32x4 acc[4][4] = {};
  for (int kt = 0; kt < SK_ / 64; ++kt) {
    float4 va[4][2];
    #pragma unroll
    for (int i = 0; i < 4; ++i) {          // issue E loads early (overlap w/ prev MFMA)
      int s = t + i * 256;
      int row = s >> 3, c16 = s & 7;
      const float* g = Eb + (size_t)row * SK_ + kt * 64 + c16 * 8;
      va[i][0] = *(const float4*)g;
      va[i][1] = *(const float4*)(g + 4);
    }
    __syncthreads();                       // prev tile's reads done
    #pragma unroll
    for (int i = 0; i < 4; ++i) {
      int s = t + i * 256;
      int row = s >> 3, c16 = s & 7;
      int c16s = c16 ^ (row & 7);
      ushort8 o;
      o[0] = f2bf(va[i][0].x); o[1] = f2bf(va[i][0].y);
      o[2] = f2bf(va[i][0].z); o[3] = f2bf(va[i][0].w);
      o[4] = f2bf(va[i][1].x); o[5] = f2bf(va[i][1].y);
      o[6] = f2bf(va[i][1].z); o[7] = f2bf(va[i][1].w);
      *(ushort8*)((char*)As + row * 128 + c16s * 16) = o;
      gload_lds16(Vb + (size_t)row * SK_ + kt * 64 + c16s * 8, (char*)Bs + s * 16);
    }
    __syncthreads();
    #pragma unroll
    for (int kk = 0; kk < 2; ++kk) {
      short8 a[4], bf[4];
      #pragma unroll
      for (int mi = 0; mi < 4; ++mi) {
        int row = (wm << 6) + (mi << 4) + (lane & 15);
        int c = ((kk << 2) + (lane >> 4)) ^ (row & 7);
        a[mi] = *(const short8*)((const char*)As + row * 128 + c * 16);
      }
      #pragma unroll
      for (int ni = 0; ni < 4; ++ni) {
        int col = (wn << 6) + (ni << 4) + (lane & 15);
        int c = ((kk << 2) + (lane >> 4)) ^ (col & 7);
        bf[ni] = *(const short8*)((const char*)Bs + col * 128 + c * 16);
      }
      #pragma unroll
      for (int mi = 0; mi < 4; ++mi)
        #pragma unroll
        for (int ni = 0; ni < 4; ++ni)
          acc[mi][ni] = __builtin_amdgcn_mfma_f32_16x16x32_bf16(a[mi], bf[ni], acc[mi][ni], 0, 0, 0);
    }
  }

  float* Ob = Out + ((size_t)bz * SQ_ + by * 128) * D_ + bx * 128;
  const int r0 = (lane >> 4) << 2;
  const int cl = lane & 15;
  #pragma unroll
  for (int mi = 0; mi < 4; ++mi) {
    #pragma unroll
    for (int r = 0; r < 4; ++r) {
      int rl = (wm << 6) + (mi << 4) + r0 + r;
      float rinv = 1.0f / rss[rl];
      #pragma unroll
      for (int ni = 0; ni < 4; ++ni)
        Ob[(size_t)rl * D_ + (wn << 6) + (ni << 4) + cl] = acc[mi][ni][r] * rinv;
    }
  }
}

// ---------------- normalize weights in place ----------------
__global__ void norm_kernel(float* __restrict__ W, const float* __restrict__ rowsum) {
  const size_t total4 = (size_t)B_ * SQ_ * SK_ / 4;
  for (size_t i = (size_t)blockIdx.x * blockDim.x + threadIdx.x; i < total4;
       i += (size_t)gridDim.x * blockDim.x) {
    float4 v = ((const float4*)W)[i];
    float rinv = 1.0f / rowsum[(i * 4) >> 11];   // 2048 cols per row
    v.x *= rinv; v.y *= rinv; v.z *= rinv; v.w *= rinv;
    ((float4*)W)[i] = v;
  }
}

extern "C" void kernel_launch(void* const* d_in, const int* in_sizes, int n_in,
                              void* d_out, int out_size, void* d_ws, size_t ws_size,
                              hipStream_t stream) {
  const float* Q     = (const float*)d_in[0];
  const float* K     = (const float*)d_in[1];
  const float* V     = (const float*)d_in[2];
  const float* alpha = (const float*)d_in[3];

  float* out = (float*)d_out;                         // [B][SQ][D]
  float* W   = out + (size_t)B_ * SQ_ * D_;           // [B][SQ][SK]

  const size_t QKV = (size_t)B_ * SQ_ * D_;           // elements per tensor
  ushort_t* Qb = (ushort_t*)d_ws;
  ushort_t* Kb = Qb + QKV;
  ushort_t* VT = Kb + QKV;
  float* q2     = (float*)(VT + QKV);
  float* k2     = q2 + B_ * SQ_;
  float* rowsum = k2 + B_ * SK_;

  hipMemsetAsync(rowsum, 0, (size_t)B_ * SQ_ * sizeof(float), stream);

  prep_qk<<<dim3(B_ * SQ_), 256, 0, stream>>>(Q, K, Qb, Kb, q2, k2);
  prep_vt<<<dim3(SK_ / 64, D_ / 64, B_), 256, 0, stream>>>(V, VT);
  qk_kernel<<<dim3(SK_ / 128, SQ_ / 128, B_), 256, 0, stream>>>(Qb, Kb, q2, k2, alpha, W, rowsum);
  pv_kernel<<<dim3(D_ / 128, SQ_ / 128, B_), 256, 0, stream>>>(W, VT, rowsum, out);
  norm_kernel<<<dim3(4096), 256, 0, stream>>>(W, rowsum);
}

// Round 2
// 368.988 us; speedup vs baseline: 1.3006x; 1.3006x over previous
//
#include <hip/hip_runtime.h>
#include <stdint.h>

#define B_  8
#define SQ_ 2048
#define SK_ 2048
#define D_  512

typedef unsigned short ushort_t;
typedef __attribute__((ext_vector_type(8))) short          short8;
typedef __attribute__((ext_vector_type(8))) unsigned short ushort8;
typedef __attribute__((ext_vector_type(4))) float          f32x4;

__device__ __forceinline__ unsigned short f2bf(float x) {
  union { float f; unsigned u; } v; v.f = x;
  unsigned r = v.u + 0x7FFFu + ((v.u >> 16) & 1u);   // RNE, finite inputs only
  return (unsigned short)(r >> 16);
}

// async global->LDS, 16B per lane. LDS dest is wave-uniform base + lane*16.
__device__ __forceinline__ void gload_lds16(const void* g, void* l) {
  __builtin_amdgcn_global_load_lds(
      (__attribute__((address_space(1))) void*)(uintptr_t)g,
      (__attribute__((address_space(3))) void*)l, 16, 0, 0);
}

// ---------------- prep: Q,K f32 -> bf16 + row sum-of-squares ----------------
__global__ void prep_qk(const float* __restrict__ Q, const float* __restrict__ K,
                        ushort_t* __restrict__ Qb, ushort_t* __restrict__ Kb,
                        float* __restrict__ q2, float* __restrict__ k2) {
  const int t = threadIdx.x;
  const int rloc = t >> 7;                 // 0/1: which of the 2 rows
  const int row  = blockIdx.x * 2 + rloc;  // 0..32767 (Q rows then K rows)
  const bool isK = row >= B_ * SQ_;
  const int r = isK ? row - B_ * SQ_ : row;
  const float*    src = (isK ? K : Q) + (size_t)r * D_;
  ushort_t*       dst = (isK ? Kb : Qb) + (size_t)r * D_;
  float*          d2  = isK ? k2 : q2;

  const int c = (t & 127) * 4;
  float4 v = *(const float4*)(src + c);
  ushort4 o;
  o.x = f2bf(v.x); o.y = f2bf(v.y); o.z = f2bf(v.z); o.w = f2bf(v.w);
  *(ushort4*)(dst + c) = o;

  float s = v.x * v.x + v.y * v.y + v.z * v.z + v.w * v.w;
  for (int off = 32; off; off >>= 1) s += __shfl_down(s, off);
  __shared__ float ps[4];
  if ((t & 63) == 0) ps[t >> 6] = s;
  __syncthreads();
  if ((t & 127) == 0) d2[r] = ps[rloc * 2] + ps[rloc * 2 + 1];
}

// ---------------- prep: V [B][SK][D] f32 -> VT [B][D][SK] bf16 ----------------
__global__ void prep_vt(const float* __restrict__ V, ushort_t* __restrict__ VT) {
  const int b  = blockIdx.z;
  const int k0 = blockIdx.x * 64;
  const int d0 = blockIdx.y * 64;
  __shared__ __align__(16) ushort_t tile[64][68];
  const int t = threadIdx.x;
  const float* src = V + (size_t)b * SK_ * D_;
  #pragma unroll
  for (int i = 0; i < 4; ++i) {
    int kl = (t >> 4) + i * 16;
    int dl = (t & 15) * 4;
    float4 v = *(const float4*)(src + (size_t)(k0 + kl) * D_ + d0 + dl);
    tile[kl][dl]     = f2bf(v.x);
    tile[kl][dl + 1] = f2bf(v.y);
    tile[kl][dl + 2] = f2bf(v.z);
    tile[kl][dl + 3] = f2bf(v.w);
  }
  __syncthreads();
  ushort_t* dstb = VT + (size_t)b * D_ * SK_;
  #pragma unroll
  for (int j = 0; j < 2; ++j) {
    int chunk = t + j * 256;
    int dl = chunk >> 3;
    int kc = (chunk & 7) << 3;
    ushort8 o;
    #pragma unroll
    for (int m = 0; m < 8; ++m) o[m] = tile[kc + m][dl];
    *(ushort8*)(dstb + (size_t)(d0 + dl) * SK_ + k0 + kc) = o;
  }
}

// ---------------- QK^T + gaussian-kernel epilogue ----------------
// BF16E=1: store unnormalized numerators E as bf16 into ws.
// BF16E=0: store f32 into W region of d_out (fallback, small ws).
template <int BF16E>
__global__ __launch_bounds__(256) void qk_kernel(
    const ushort_t* __restrict__ Qb, const ushort_t* __restrict__ Kb,
    const float* __restrict__ q2, const float* __restrict__ k2,
    const float* __restrict__ alphap,
    float* __restrict__ Wf, ushort_t* __restrict__ Ebf,
    float* __restrict__ rowsum) {
  __shared__ __align__(16) ushort_t As[8192];   // 128 x 64 bf16 (swizzled)
  __shared__ __align__(16) ushort_t Bs[8192];
  __shared__ float q2s[128], k2s[128];

  const int t = threadIdx.x;
  const int lane = t & 63, wid = t >> 6;
  const int wm = wid >> 1, wn = wid & 1;

  // XCD-aware bijective swizzle: 2048 blocks, chunk 256 -> XCD x owns batch x,
  // making Qb+Kb per batch (4 MB bf16) L2-resident per XCD.
  const int id  = blockIdx.x + 16 * blockIdx.y + 256 * blockIdx.z;
  const int swz = (id & 7) * 256 + (id >> 3);
  const int bx = swz & 15, by = (swz >> 4) & 15, bz = swz >> 8;

  const ushort_t* Aq = Qb + ((size_t)bz * SQ_ + by * 128) * D_;
  const ushort_t* Bk = Kb + ((size_t)bz * SK_ + bx * 128) * D_;

  if (t < 128) q2s[t] = q2[bz * SQ_ + by * 128 + t];
  else         k2s[t - 128] = k2[bz * SK_ + bx * 128 + (t - 128)];

  f32x4 acc[4][4] = {};
  for (int kt = 0; kt < D_ / 64; ++kt) {
    __syncthreads();
    #pragma unroll
    for (int i = 0; i < 4; ++i) {
      int s = t + i * 256;                 // 16B slot id, 1024 slots per tile
      int row = s >> 3;
      int c16 = (s & 7) ^ (row & 7);       // pre-swizzled global source column
      gload_lds16(Aq + (size_t)row * D_ + kt * 64 + c16 * 8, (char*)As + s * 16);
      gload_lds16(Bk + (size_t)row * D_ + kt * 64 + c16 * 8, (char*)Bs + s * 16);
    }
    __syncthreads();
    #pragma unroll
    for (int kk = 0; kk < 2; ++kk) {
      short8 a[4], bf[4];
      #pragma unroll
      for (int mi = 0; mi < 4; ++mi) {
        int row = (wm << 6) + (mi << 4) + (lane & 15);
        int c = ((kk << 2) + (lane >> 4)) ^ (row & 7);
        a[mi] = *(const short8*)((const char*)As + row * 128 + c * 16);
      }
      #pragma unroll
      for (int ni = 0; ni < 4; ++ni) {
        int col = (wn << 6) + (ni << 4) + (lane & 15);
        int c = ((kk << 2) + (lane >> 4)) ^ (col & 7);
        bf[ni] = *(const short8*)((const char*)Bs + col * 128 + c * 16);
      }
      #pragma unroll
      for (int mi = 0; mi < 4; ++mi)
        #pragma unroll
        for (int ni = 0; ni < 4; ++ni)
          acc[mi][ni] = __builtin_amdgcn_mfma_f32_16x16x32_bf16(a[mi], bf[ni], acc[mi][ni], 0, 0, 0);
    }
  }

  const float alpha = *alphap;
  const int r0 = (lane >> 4) << 2;
  const int cl = lane & 15;

  float k2c[4];
  #pragma unroll
  for (int ni = 0; ni < 4; ++ni) k2c[ni] = k2s[(wn << 6) + (ni << 4) + cl];

  #pragma unroll
  for (int mi = 0; mi < 4; ++mi) {
    float q2r[4];
    #pragma unroll
    for (int r = 0; r < 4; ++r) q2r[r] = q2s[(wm << 6) + (mi << 4) + r0 + r];
    float se[4] = {0.f, 0.f, 0.f, 0.f};
    #pragma unroll
    for (int ni = 0; ni < 4; ++ni) {
      int gcol = bx * 128 + (wn << 6) + (ni << 4) + cl;
      #pragma unroll
      for (int r = 0; r < 4; ++r) {
        int rl = (wm << 6) + (mi << 4) + r0 + r;
        float sq = fmaxf(q2r[r] + k2c[ni] - 2.0f * acc[mi][ni][r], 0.0f);
        float kv = __expf(-alpha * sq);    // gaussian "kernel" value, in [0,1]
        float e  = __expf(kv);             // softmax numerator (no max needed)
        size_t idx = (size_t)((size_t)bz * SQ_ + by * 128 + rl) * SK_ + gcol;
        if (BF16E) Ebf[idx] = f2bf(e);
        else       Wf[idx]  = e;
        se[r] += e;
      }
    }
    #pragma unroll
    for (int r = 0; r < 4; ++r) {
      float s = se[r];
      for (int off = 1; off < 16; off <<= 1) s += __shfl_xor(s, off);
      if (cl == 0)
        atomicAdd(&rowsum[bz * SQ_ + by * 128 + (wm << 6) + (mi << 4) + r0 + r], s);
    }
  }
}

// ---------------- PV (bf16 path): out = E_bf16 * VT / rowsum ----------------
__global__ __launch_bounds__(256) void pv_bf16(
    const ushort_t* __restrict__ Eb, const ushort_t* __restrict__ VT,
    const float* __restrict__ rowsum, float* __restrict__ Out) {
  __shared__ __align__(16) ushort_t As[8192];   // E tile 128q x 64k (swizzled)
  __shared__ __align__(16) ushort_t Bs[8192];   // VT tile 128d x 64k (swizzled)
  __shared__ float rss[128];

  const int t = threadIdx.x;
  const int lane = t & 63, wid = t >> 6;
  const int wm = wid >> 1, wn = wid & 1;

  // XCD swizzle: 512 blocks, chunk 64 -> XCD x owns batch x.
  const int id  = blockIdx.x + 4 * blockIdx.y + 64 * blockIdx.z;
  const int swz = (id & 7) * 64 + (id >> 3);
  const int bx = swz & 3, by = (swz >> 2) & 15, bz = swz >> 6;

  const ushort_t* Ebb = Eb + ((size_t)bz * SQ_ + by * 128) * SK_;
  const ushort_t* Vb  = VT + ((size_t)bz * D_ + bx * 128) * SK_;

  if (t < 128) rss[t] = rowsum[bz * SQ_ + by * 128 + t];

  f32x4 acc[4][4] = {};
  for (int kt = 0; kt < SK_ / 64; ++kt) {
    __syncthreads();
    #pragma unroll
    for (int i = 0; i < 4; ++i) {
      int s = t + i * 256;
      int row = s >> 3;
      int c16 = (s & 7) ^ (row & 7);
      gload_lds16(Ebb + (size_t)row * SK_ + kt * 64 + c16 * 8, (char*)As + s * 16);
      gload_lds16(Vb  + (size_t)row * SK_ + kt * 64 + c16 * 8, (char*)Bs + s * 16);
    }
    __syncthreads();
    #pragma unroll
    for (int kk = 0; kk < 2; ++kk) {
      short8 a[4], bf[4];
      #pragma unroll
      for (int mi = 0; mi < 4; ++mi) {
        int row = (wm << 6) + (mi << 4) + (lane & 15);
        int c = ((kk << 2) + (lane >> 4)) ^ (row & 7);
        a[mi] = *(const short8*)((const char*)As + row * 128 + c * 16);
      }
      #pragma unroll
      for (int ni = 0; ni < 4; ++ni) {
        int col = (wn << 6) + (ni << 4) + (lane & 15);
        int c = ((kk << 2) + (lane >> 4)) ^ (col & 7);
        bf[ni] = *(const short8*)((const char*)Bs + col * 128 + c * 16);
      }
      #pragma unroll
      for (int mi = 0; mi < 4; ++mi)
        #pragma unroll
        for (int ni = 0; ni < 4; ++ni)
          acc[mi][ni] = __builtin_amdgcn_mfma_f32_16x16x32_bf16(a[mi], bf[ni], acc[mi][ni], 0, 0, 0);
    }
  }

  float* Ob = Out + ((size_t)bz * SQ_ + by * 128) * D_ + bx * 128;
  const int r0 = (lane >> 4) << 2;
  const int cl = lane & 15;
  #pragma unroll
  for (int mi = 0; mi < 4; ++mi) {
    #pragma unroll
    for (int r = 0; r < 4; ++r) {
      int rl = (wm << 6) + (mi << 4) + r0 + r;
      float rinv = 1.0f / rss[rl];
      #pragma unroll
      for (int ni = 0; ni < 4; ++ni)
        Ob[(size_t)rl * D_ + (wn << 6) + (ni << 4) + cl] = acc[mi][ni][r] * rinv;
    }
  }
}

// ---------------- PV (f32 fallback): out = E_f32 * VT / rowsum ----------------
__global__ __launch_bounds__(256) void pv_f32(
    const float* __restrict__ E, const ushort_t* __restrict__ VT,
    const float* __restrict__ rowsum, float* __restrict__ Out) {
  __shared__ __align__(16) ushort_t As[8192];
  __shared__ __align__(16) ushort_t Bs[8192];
  __shared__ float rss[128];

  const int t = threadIdx.x;
  const int lane = t & 63, wid = t >> 6;
  const int wm = wid >> 1, wn = wid & 1;
  const int bx = blockIdx.x, by = blockIdx.y, bz = blockIdx.z;

  const float*    Eb = E + ((size_t)bz * SQ_ + by * 128) * SK_;
  const ushort_t* Vb = VT + ((size_t)bz * D_ + bx * 128) * SK_;

  if (t < 128) rss[t] = rowsum[bz * SQ_ + by * 128 + t];

  f32x4 acc[4][4] = {};
  for (int kt = 0; kt < SK_ / 64; ++kt) {
    float4 va[4][2];
    #pragma unroll
    for (int i = 0; i < 4; ++i) {
      int s = t + i * 256;
      int row = s >> 3, c16 = s & 7;
      const float* g = Eb + (size_t)row * SK_ + kt * 64 + c16 * 8;
      va[i][0] = *(const float4*)g;
      va[i][1] = *(const float4*)(g + 4);
    }
    __syncthreads();
    #pragma unroll
    for (int i = 0; i < 4; ++i) {
      int s = t + i * 256;
      int row = s >> 3, c16 = s & 7;
      int c16s = c16 ^ (row & 7);
      ushort8 o;
      o[0] = f2bf(va[i][0].x); o[1] = f2bf(va[i][0].y);
      o[2] = f2bf(va[i][0].z); o[3] = f2bf(va[i][0].w);
      o[4] = f2bf(va[i][1].x); o[5] = f2bf(va[i][1].y);
      o[6] = f2bf(va[i][1].z); o[7] = f2bf(va[i][1].w);
      *(ushort8*)((char*)As + row * 128 + c16s * 16) = o;
      gload_lds16(Vb + (size_t)row * SK_ + kt * 64 + c16s * 8, (char*)Bs + s * 16);
    }
    __syncthreads();
    #pragma unroll
    for (int kk = 0; kk < 2; ++kk) {
      short8 a[4], bf[4];
      #pragma unroll
      for (int mi = 0; mi < 4; ++mi) {
        int row = (wm << 6) + (mi << 4) + (lane & 15);
        int c = ((kk << 2) + (lane >> 4)) ^ (row & 7);
        a[mi] = *(const short8*)((const char*)As + row * 128 + c * 16);
      }
      #pragma unroll
      for (int ni = 0; ni < 4; ++ni) {
        int col = (wn << 6) + (ni << 4) + (lane & 15);
        int c = ((kk << 2) + (lane >> 4)) ^ (col & 7);
        bf[ni] = *(const short8*)((const char*)Bs + col * 128 + c * 16);
      }
      #pragma unroll
      for (int mi = 0; mi < 4; ++mi)
        #pragma unroll
        for (int ni = 0; ni < 4; ++ni)
          acc[mi][ni] = __builtin_amdgcn_mfma_f32_16x16x32_bf16(a[mi], bf[ni], acc[mi][ni], 0, 0, 0);
    }
  }

  float* Ob = Out + ((size_t)bz * SQ_ + by * 128) * D_ + bx * 128;
  const int r0 = (lane >> 4) << 2;
  const int cl = lane & 15;
  #pragma unroll
  for (int mi = 0; mi < 4; ++mi) {
    #pragma unroll
    for (int r = 0; r < 4; ++r) {
      int rl = (wm << 6) + (mi << 4) + r0 + r;
      float rinv = 1.0f / rss[rl];
      #pragma unroll
      for (int ni = 0; ni < 4; ++ni)
        Ob[(size_t)rl * D_ + (wn << 6) + (ni << 4) + cl] = acc[mi][ni][r] * rinv;
    }
  }
}

// ---------------- normalize: W_f32 = E_bf16 * rinv ----------------
__global__ void norm_bf16(const ushort_t* __restrict__ E,
                          const float* __restrict__ rowsum,
                          float* __restrict__ W) {
  const size_t total8 = (size_t)B_ * SQ_ * SK_ / 8;
  for (size_t g = (size_t)blockIdx.x * blockDim.x + threadIdx.x; g < total8;
       g += (size_t)gridDim.x * blockDim.x) {
    ushort8 e = *(const ushort8*)(E + g * 8);
    float rinv = 1.0f / rowsum[g >> 8];    // 256 groups of 8 per 2048-col row
    float4 lo, hi;
    lo.x = __uint_as_float((unsigned)e[0] << 16) * rinv;
    lo.y = __uint_as_float((unsigned)e[1] << 16) * rinv;
    lo.z = __uint_as_float((unsigned)e[2] << 16) * rinv;
    lo.w = __uint_as_float((unsigned)e[3] << 16) * rinv;
    hi.x = __uint_as_float((unsigned)e[4] << 16) * rinv;
    hi.y = __uint_as_float((unsigned)e[5] << 16) * rinv;
    hi.z = __uint_as_float((unsigned)e[6] << 16) * rinv;
    hi.w = __uint_as_float((unsigned)e[7] << 16) * rinv;
    *(float4*)(W + g * 8)     = lo;
    *(float4*)(W + g * 8 + 4) = hi;
  }
}

// ---------------- normalize in place (f32 fallback) ----------------
__global__ void norm_f32(float* __restrict__ W, const float* __restrict__ rowsum) {
  const size_t total4 = (size_t)B_ * SQ_ * SK_ / 4;
  for (size_t i = (size_t)blockIdx.x * blockDim.x + threadIdx.x; i < total4;
       i += (size_t)gridDim.x * blockDim.x) {
    float4 v = ((const float4*)W)[i];
    float rinv = 1.0f / rowsum[i >> 9];    // 512 float4 per row
    v.x *= rinv; v.y *= rinv; v.z *= rinv; v.w *= rinv;
    ((float4*)W)[i] = v;
  }
}

extern "C" void kernel_launch(void* const* d_in, const int* in_sizes, int n_in,
                              void* d_out, int out_size, void* d_ws, size_t ws_size,
                              hipStream_t stream) {
  const float* Q     = (const float*)d_in[0];
  const float* K     = (const float*)d_in[1];
  const float* V     = (const float*)d_in[2];
  const float* alpha = (const float*)d_in[3];

  float* out = (float*)d_out;                         // [B][SQ][D]
  float* W   = out + (size_t)B_ * SQ_ * D_;           // [B][SQ][SK]

  const size_t QKV = (size_t)B_ * SQ_ * D_;           // elements per tensor
  const size_t NW  = (size_t)B_ * SQ_ * SK_;          // weight elements
  ushort_t* Qb = (ushort_t*)d_ws;
  ushort_t* Kb = Qb + QKV;
  ushort_t* VT = Kb + QKV;

  const size_t need_bf16 = (3 * QKV + NW) * sizeof(ushort_t)
                         + (size_t)(2 * B_ * SQ_ + B_ * SK_) * sizeof(float);
  const bool use_bf16 = ws_size >= need_bf16;

  ushort_t* Eb = VT + QKV;                            // bf16 path only
  float* fbase = use_bf16 ? (float*)(Eb + NW) : (float*)(VT + QKV);
  float* q2     = fbase;
  float* k2     = q2 + B_ * SQ_;
  float* rowsum = k2 + B_ * SK_;

  hipMemsetAsync(rowsum, 0, (size_t)B_ * SQ_ * sizeof(float), stream);

  prep_qk<<<dim3(B_ * SQ_), 256, 0, stream>>>(Q, K, Qb, Kb, q2, k2);
  prep_vt<<<dim3(SK_ / 64, D_ / 64, B_), 256, 0, stream>>>(V, VT);

  if (use_bf16) {
    qk_kernel<1><<<dim3(SK_ / 128, SQ_ / 128, B_), 256, 0, stream>>>(
        Qb, Kb, q2, k2, alpha, nullptr, Eb, rowsum);
    pv_bf16<<<dim3(D_ / 128, SQ_ / 128, B_), 256, 0, stream>>>(Eb, VT, rowsum, out);
    norm_bf16<<<dim3(2048), 256, 0, stream>>>(Eb, rowsum, W);
  } else {
    qk_kernel<0><<<dim3(SK_ / 128, SQ_ / 128, B_), 256, 0, stream>>>(
        Qb, Kb, q2, k2, alpha, W, nullptr, rowsum);
    pv_f32<<<dim3(D_ / 128, SQ_ / 128, B_), 256, 0, stream>>>(W, VT, rowsum, out);
    norm_f32<<<dim3(4096), 256, 0, stream>>>(W, rowsum);
  }
}

// Round 3
// 353.947 us; speedup vs baseline: 1.3559x; 1.0425x over previous
//
#include <hip/hip_runtime.h>
#include <stdint.h>

#define B_  8
#define SQ_ 2048
#define SK_ 2048
#define D_  512

typedef unsigned short ushort_t;
typedef __attribute__((ext_vector_type(8))) short          short8;
typedef __attribute__((ext_vector_type(8))) unsigned short ushort8;
typedef __attribute__((ext_vector_type(4))) float          f32x4;

__device__ __forceinline__ unsigned short f2bf(float x) {
  union { float f; unsigned u; } v; v.f = x;
  unsigned r = v.u + 0x7FFFu + ((v.u >> 16) & 1u);   // RNE, finite inputs only
  return (unsigned short)(r >> 16);
}

// async global->LDS, 16B per lane. LDS dest is wave-uniform base + lane*16.
__device__ __forceinline__ void gload_lds16(const void* g, void* l) {
  __builtin_amdgcn_global_load_lds(
      (__attribute__((address_space(1))) void*)(uintptr_t)g,
      (__attribute__((address_space(3))) void*)l, 16, 0, 0);
}

// ---------------- prep: Q,K f32 -> bf16 + row sum-of-squares ----------------
__global__ void prep_qk(const float* __restrict__ Q, const float* __restrict__ K,
                        ushort_t* __restrict__ Qb, ushort_t* __restrict__ Kb,
                        float* __restrict__ q2, float* __restrict__ k2) {
  const int t = threadIdx.x;
  const int rloc = t >> 7;                 // 0/1: which of the 2 rows
  const int row  = blockIdx.x * 2 + rloc;  // 0..32767 (Q rows then K rows)
  const bool isK = row >= B_ * SQ_;
  const int r = isK ? row - B_ * SQ_ : row;
  const float*    src = (isK ? K : Q) + (size_t)r * D_;
  ushort_t*       dst = (isK ? Kb : Qb) + (size_t)r * D_;
  float*          d2  = isK ? k2 : q2;

  const int c = (t & 127) * 4;
  float4 v = *(const float4*)(src + c);
  ushort4 o;
  o.x = f2bf(v.x); o.y = f2bf(v.y); o.z = f2bf(v.z); o.w = f2bf(v.w);
  *(ushort4*)(dst + c) = o;

  float s = v.x * v.x + v.y * v.y + v.z * v.z + v.w * v.w;
  for (int off = 32; off; off >>= 1) s += __shfl_down(s, off);
  __shared__ float ps[4];
  if ((t & 63) == 0) ps[t >> 6] = s;
  __syncthreads();
  if ((t & 127) == 0) d2[r] = ps[rloc * 2] + ps[rloc * 2 + 1];
}

// ---------------- prep: V [B][SK][D] f32 -> VT [B][D][SK] bf16 ----------------
__global__ void prep_vt(const float* __restrict__ V, ushort_t* __restrict__ VT) {
  const int b  = blockIdx.z;
  const int k0 = blockIdx.x * 64;
  const int d0 = blockIdx.y * 64;
  __shared__ __align__(16) ushort_t tile[64][68];
  const int t = threadIdx.x;
  const float* src = V + (size_t)b * SK_ * D_;
  #pragma unroll
  for (int i = 0; i < 4; ++i) {
    int kl = (t >> 4) + i * 16;
    int dl = (t & 15) * 4;
    float4 v = *(const float4*)(src + (size_t)(k0 + kl) * D_ + d0 + dl);
    tile[kl][dl]     = f2bf(v.x);
    tile[kl][dl + 1] = f2bf(v.y);
    tile[kl][dl + 2] = f2bf(v.z);
    tile[kl][dl + 3] = f2bf(v.w);
  }
  __syncthreads();
  ushort_t* dstb = VT + (size_t)b * D_ * SK_;
  #pragma unroll
  for (int j = 0; j < 2; ++j) {
    int chunk = t + j * 256;
    int dl = chunk >> 3;
    int kc = (chunk & 7) << 3;
    ushort8 o;
    #pragma unroll
    for (int m = 0; m < 8; ++m) o[m] = tile[kc + m][dl];
    *(ushort8*)(dstb + (size_t)(d0 + dl) * SK_ + k0 + kc) = o;
  }
}

// ---------------- QK^T + gaussian-kernel epilogue ----------------
// BF16E=1: store unnormalized numerators E as bf16 into ws.
// BF16E=0: store f32 into W region of d_out (fallback, small ws).
template <int BF16E>
__global__ __launch_bounds__(256) void qk_kernel(
    const ushort_t* __restrict__ Qb, const ushort_t* __restrict__ Kb,
    const float* __restrict__ q2, const float* __restrict__ k2,
    const float* __restrict__ alphap,
    float* __restrict__ Wf, ushort_t* __restrict__ Ebf,
    float* __restrict__ rowsum) {
  __shared__ __align__(16) ushort_t As[2][8192];  // dbuf 128x64 bf16 (swizzled)
  __shared__ __align__(16) ushort_t Bs[2][8192];
  __shared__ float q2s[128], k2s[128];

  const int t = threadIdx.x;
  const int lane = t & 63, wid = t >> 6;
  const int wm = wid >> 1, wn = wid & 1;

  // XCD-aware bijective swizzle: 2048 blocks, chunk 256 -> XCD x owns batch x.
  const int id  = blockIdx.x + 16 * blockIdx.y + 256 * blockIdx.z;
  const int swz = (id & 7) * 256 + (id >> 3);
  const int bx = swz & 15, by = (swz >> 4) & 15, bz = swz >> 8;

  const ushort_t* Aq = Qb + ((size_t)bz * SQ_ + by * 128) * D_;
  const ushort_t* Bk = Kb + ((size_t)bz * SK_ + bx * 128) * D_;

  if (t < 128) q2s[t] = q2[bz * SQ_ + by * 128 + t];
  else         k2s[t - 128] = k2[bz * SK_ + bx * 128 + (t - 128)];

  // 2-phase pipeline: issue next tile's loads before computing current.
  #define QK_STAGE(buf, kt)                                                     \
    _Pragma("unroll")                                                           \
    for (int i = 0; i < 4; ++i) {                                               \
      int s = t + i * 256;                                                      \
      int row = s >> 3;                                                         \
      int c16 = (s & 7) ^ (row & 7);                                            \
      gload_lds16(Aq + (size_t)row * D_ + (kt) * 64 + c16 * 8,                  \
                  (char*)As[buf] + s * 16);                                     \
      gload_lds16(Bk + (size_t)row * D_ + (kt) * 64 + c16 * 8,                  \
                  (char*)Bs[buf] + s * 16);                                     \
    }

  QK_STAGE(0, 0);
  __syncthreads();

  f32x4 acc[4][4] = {};
  #pragma unroll
  for (int kt = 0; kt < 8; ++kt) {
    const int cur = kt & 1;
    if (kt < 7) { QK_STAGE(cur ^ 1, kt + 1); }
    #pragma unroll
    for (int kk = 0; kk < 2; ++kk) {
      short8 a[4], bf[4];
      #pragma unroll
      for (int mi = 0; mi < 4; ++mi) {
        int row = (wm << 6) + (mi << 4) + (lane & 15);
        int c = ((kk << 2) + (lane >> 4)) ^ (row & 7);
        a[mi] = *(const short8*)((const char*)As[cur] + row * 128 + c * 16);
      }
      #pragma unroll
      for (int ni = 0; ni < 4; ++ni) {
        int col = (wn << 6) + (ni << 4) + (lane & 15);
        int c = ((kk << 2) + (lane >> 4)) ^ (col & 7);
        bf[ni] = *(const short8*)((const char*)Bs[cur] + col * 128 + c * 16);
      }
      #pragma unroll
      for (int mi = 0; mi < 4; ++mi)
        #pragma unroll
        for (int ni = 0; ni < 4; ++ni)
          acc[mi][ni] = __builtin_amdgcn_mfma_f32_16x16x32_bf16(a[mi], bf[ni], acc[mi][ni], 0, 0, 0);
    }
    __syncthreads();   // drains vmcnt for next tile + protects buffer reuse
  }
  #undef QK_STAGE

  const float alpha = *alphap;
  const int r0 = (lane >> 4) << 2;
  const int cl = lane & 15;

  float k2c[4];
  #pragma unroll
  for (int ni = 0; ni < 4; ++ni) k2c[ni] = k2s[(wn << 6) + (ni << 4) + cl];

  #pragma unroll
  for (int mi = 0; mi < 4; ++mi) {
    float q2r[4];
    #pragma unroll
    for (int r = 0; r < 4; ++r) q2r[r] = q2s[(wm << 6) + (mi << 4) + r0 + r];
    float se[4] = {0.f, 0.f, 0.f, 0.f};
    #pragma unroll
    for (int ni = 0; ni < 4; ++ni) {
      int gcol = bx * 128 + (wn << 6) + (ni << 4) + cl;
      float x[4], e[4];
      #pragma unroll
      for (int r = 0; r < 4; ++r) {
        float sq = fmaxf(q2r[r] + k2c[ni] - 2.0f * acc[mi][ni][r], 0.0f);
        x[r] = -alpha * sq;
      }
      // exp(exp(x)) == 1.0f exactly when x < -20 (kv < 2e-9; 1+kv rounds to 1).
      int small = (x[0] < -20.f) & (x[1] < -20.f) & (x[2] < -20.f) & (x[3] < -20.f);
      if (__all(small)) {
        #pragma unroll
        for (int r = 0; r < 4; ++r) e[r] = 1.0f;
      } else {
        #pragma unroll
        for (int r = 0; r < 4; ++r) e[r] = __expf(__expf(x[r]));
      }
      #pragma unroll
      for (int r = 0; r < 4; ++r) {
        int rl = (wm << 6) + (mi << 4) + r0 + r;
        size_t idx = (size_t)((size_t)bz * SQ_ + by * 128 + rl) * SK_ + gcol;
        if (BF16E) Ebf[idx] = f2bf(e[r]);
        else       Wf[idx]  = e[r];
        se[r] += e[r];
      }
    }
    #pragma unroll
    for (int r = 0; r < 4; ++r) {
      float s = se[r];
      for (int off = 1; off < 16; off <<= 1) s += __shfl_xor(s, off);
      if (cl == 0)
        atomicAdd(&rowsum[bz * SQ_ + by * 128 + (wm << 6) + (mi << 4) + r0 + r], s);
    }
  }
}

// ---------------- PV (bf16): out = E*VT/rowsum, W written from E tiles ----------------
__global__ __launch_bounds__(256) void pv_bf16(
    const ushort_t* __restrict__ Eb, const ushort_t* __restrict__ VT,
    const float* __restrict__ rowsum, float* __restrict__ Out,
    float* __restrict__ W) {
  __shared__ __align__(16) ushort_t As[2][8192];  // E tile dbuf (swizzled)
  __shared__ __align__(16) ushort_t Bs[2][8192];  // VT tile dbuf (swizzled)
  __shared__ float rss[128];

  const int t = threadIdx.x;
  const int lane = t & 63, wid = t >> 6;
  const int wm = wid >> 1, wn = wid & 1;

  // XCD swizzle: 512 blocks, chunk 64 -> XCD x owns batch x.
  const int id  = blockIdx.x + 4 * blockIdx.y + 64 * blockIdx.z;
  const int swz = (id & 7) * 64 + (id >> 3);
  const int bx = swz & 3, by = (swz >> 2) & 15, bz = swz >> 6;

  const ushort_t* Ebb = Eb + ((size_t)bz * SQ_ + by * 128) * SK_;
  const ushort_t* Vb  = VT + ((size_t)bz * D_ + bx * 128) * SK_;
  float* Wb = W + ((size_t)bz * SQ_ + by * 128) * SK_;

  if (t < 128) rss[t] = rowsum[bz * SQ_ + by * 128 + t];
  __syncthreads();                       // rss visible before W-write uses it
  const float rinv_t = 1.0f;             // placeholder; per-row below

  #define PV_STAGE(buf, kt)                                                     \
    _Pragma("unroll")                                                           \
    for (int i = 0; i < 4; ++i) {                                               \
      int s = t + i * 256;                                                      \
      int row = s >> 3;                                                         \
      int c16 = (s & 7) ^ (row & 7);                                            \
      gload_lds16(Ebb + (size_t)row * SK_ + (kt) * 64 + c16 * 8,                \
                  (char*)As[buf] + s * 16);                                     \
      gload_lds16(Vb  + (size_t)row * SK_ + (kt) * 64 + c16 * 8,                \
                  (char*)Bs[buf] + s * 16);                                     \
    }

  PV_STAGE(0, 0);
  __syncthreads();

  const int wlo = bx * 8, whi = wlo + 8;   // this block's W kt-slice
  f32x4 acc[4][4] = {};
  for (int kt = 0; kt < 32; ++kt) {
    const int cur = kt & 1;
    if (kt < 31) { PV_STAGE(cur ^ 1, kt + 1); }

    // write W f32 = E*rinv for this kt-slice straight from the staged tile
    if (kt >= wlo && kt < whi) {
      #pragma unroll
      for (int i = 0; i < 4; ++i) {
        int s = t + i * 256;
        int row = s >> 3;
        int c16 = s & 7;
        int c16s = c16 ^ (row & 7);
        ushort8 ev = *(const ushort8*)((const char*)As[cur] + row * 128 + c16s * 16);
        float rinv = 1.0f / rss[row];
        float4 lo, hi;
        lo.x = __uint_as_float((unsigned)ev[0] << 16) * rinv;
        lo.y = __uint_as_float((unsigned)ev[1] << 16) * rinv;
        lo.z = __uint_as_float((unsigned)ev[2] << 16) * rinv;
        lo.w = __uint_as_float((unsigned)ev[3] << 16) * rinv;
        hi.x = __uint_as_float((unsigned)ev[4] << 16) * rinv;
        hi.y = __uint_as_float((unsigned)ev[5] << 16) * rinv;
        hi.z = __uint_as_float((unsigned)ev[6] << 16) * rinv;
        hi.w = __uint_as_float((unsigned)ev[7] << 16) * rinv;
        float* wp = Wb + (size_t)row * SK_ + kt * 64 + c16 * 8;
        *(float4*)wp       = lo;
        *(float4*)(wp + 4) = hi;
      }
    }

    #pragma unroll
    for (int kk = 0; kk < 2; ++kk) {
      short8 a[4], bf[4];
      #pragma unroll
      for (int mi = 0; mi < 4; ++mi) {
        int row = (wm << 6) + (mi << 4) + (lane & 15);
        int c = ((kk << 2) + (lane >> 4)) ^ (row & 7);
        a[mi] = *(const short8*)((const char*)As[cur] + row * 128 + c * 16);
      }
      #pragma unroll
      for (int ni = 0; ni < 4; ++ni) {
        int col = (wn << 6) + (ni << 4) + (lane & 15);
        int c = ((kk << 2) + (lane >> 4)) ^ (col & 7);
        bf[ni] = *(const short8*)((const char*)Bs[cur] + col * 128 + c * 16);
      }
      #pragma unroll
      for (int mi = 0; mi < 4; ++mi)
        #pragma unroll
        for (int ni = 0; ni < 4; ++ni)
          acc[mi][ni] = __builtin_amdgcn_mfma_f32_16x16x32_bf16(a[mi], bf[ni], acc[mi][ni], 0, 0, 0);
    }
    __syncthreads();
  }
  #undef PV_STAGE
  (void)rinv_t;

  float* Ob = Out + ((size_t)bz * SQ_ + by * 128) * D_ + bx * 128;
  const int r0 = (lane >> 4) << 2;
  const int cl = lane & 15;
  #pragma unroll
  for (int mi = 0; mi < 4; ++mi) {
    #pragma unroll
    for (int r = 0; r < 4; ++r) {
      int rl = (wm << 6) + (mi << 4) + r0 + r;
      float rinv = 1.0f / rss[rl];
      #pragma unroll
      for (int ni = 0; ni < 4; ++ni)
        Ob[(size_t)rl * D_ + (wn << 6) + (ni << 4) + cl] = acc[mi][ni][r] * rinv;
    }
  }
}

// ---------------- PV (f32 fallback): out = E_f32 * VT / rowsum ----------------
__global__ __launch_bounds__(256) void pv_f32(
    const float* __restrict__ E, const ushort_t* __restrict__ VT,
    const float* __restrict__ rowsum, float* __restrict__ Out) {
  __shared__ __align__(16) ushort_t As[8192];
  __shared__ __align__(16) ushort_t Bs[8192];
  __shared__ float rss[128];

  const int t = threadIdx.x;
  const int lane = t & 63, wid = t >> 6;
  const int wm = wid >> 1, wn = wid & 1;
  const int bx = blockIdx.x, by = blockIdx.y, bz = blockIdx.z;

  const float*    Eb = E + ((size_t)bz * SQ_ + by * 128) * SK_;
  const ushort_t* Vb = VT + ((size_t)bz * D_ + bx * 128) * SK_;

  if (t < 128) rss[t] = rowsum[bz * SQ_ + by * 128 + t];

  f32x4 acc[4][4] = {};
  for (int kt = 0; kt < SK_ / 64; ++kt) {
    float4 va[4][2];
    #pragma unroll
    for (int i = 0; i < 4; ++i) {
      int s = t + i * 256;
      int row = s >> 3, c16 = s & 7;
      const float* g = Eb + (size_t)row * SK_ + kt * 64 + c16 * 8;
      va[i][0] = *(const float4*)g;
      va[i][1] = *(const float4*)(g + 4);
    }
    __syncthreads();
    #pragma unroll
    for (int i = 0; i < 4; ++i) {
      int s = t + i * 256;
      int row = s >> 3, c16 = s & 7;
      int c16s = c16 ^ (row & 7);
      ushort8 o;
      o[0] = f2bf(va[i][0].x); o[1] = f2bf(va[i][0].y);
      o[2] = f2bf(va[i][0].z); o[3] = f2bf(va[i][0].w);
      o[4] = f2bf(va[i][1].x); o[5] = f2bf(va[i][1].y);
      o[6] = f2bf(va[i][1].z); o[7] = f2bf(va[i][1].w);
      *(ushort8*)((char*)As + row * 128 + c16s * 16) = o;
      gload_lds16(Vb + (size_t)row * SK_ + kt * 64 + c16s * 8, (char*)Bs + s * 16);
    }
    __syncthreads();
    #pragma unroll
    for (int kk = 0; kk < 2; ++kk) {
      short8 a[4], bf[4];
      #pragma unroll
      for (int mi = 0; mi < 4; ++mi) {
        int row = (wm << 6) + (mi << 4) + (lane & 15);
        int c = ((kk << 2) + (lane >> 4)) ^ (row & 7);
        a[mi] = *(const short8*)((const char*)As + row * 128 + c * 16);
      }
      #pragma unroll
      for (int ni = 0; ni < 4; ++ni) {
        int col = (wn << 6) + (ni << 4) + (lane & 15);
        int c = ((kk << 2) + (lane >> 4)) ^ (col & 7);
        bf[ni] = *(const short8*)((const char*)Bs + col * 128 + c * 16);
      }
      #pragma unroll
      for (int mi = 0; mi < 4; ++mi)
        #pragma unroll
        for (int ni = 0; ni < 4; ++ni)
          acc[mi][ni] = __builtin_amdgcn_mfma_f32_16x16x32_bf16(a[mi], bf[ni], acc[mi][ni], 0, 0, 0);
    }
  }

  float* Ob = Out + ((size_t)bz * SQ_ + by * 128) * D_ + bx * 128;
  const int r0 = (lane >> 4) << 2;
  const int cl = lane & 15;
  #pragma unroll
  for (int mi = 0; mi < 4; ++mi) {
    #pragma unroll
    for (int r = 0; r < 4; ++r) {
      int rl = (wm << 6) + (mi << 4) + r0 + r;
      float rinv = 1.0f / rss[rl];
      #pragma unroll
      for (int ni = 0; ni < 4; ++ni)
        Ob[(size_t)rl * D_ + (wn << 6) + (ni << 4) + cl] = acc[mi][ni][r] * rinv;
    }
  }
}

// ---------------- normalize in place (f32 fallback) ----------------
__global__ void norm_f32(float* __restrict__ W, const float* __restrict__ rowsum) {
  const size_t total4 = (size_t)B_ * SQ_ * SK_ / 4;
  for (size_t i = (size_t)blockIdx.x * blockDim.x + threadIdx.x; i < total4;
       i += (size_t)gridDim.x * blockDim.x) {
    float4 v = ((const float4*)W)[i];
    float rinv = 1.0f / rowsum[i >> 9];    // 512 float4 per row
    v.x *= rinv; v.y *= rinv; v.z *= rinv; v.w *= rinv;
    ((float4*)W)[i] = v;
  }
}

extern "C" void kernel_launch(void* const* d_in, const int* in_sizes, int n_in,
                              void* d_out, int out_size, void* d_ws, size_t ws_size,
                              hipStream_t stream) {
  const float* Q     = (const float*)d_in[0];
  const float* K     = (const float*)d_in[1];
  const float* V     = (const float*)d_in[2];
  const float* alpha = (const float*)d_in[3];

  float* out = (float*)d_out;                         // [B][SQ][D]
  float* W   = out + (size_t)B_ * SQ_ * D_;           // [B][SQ][SK]

  const size_t QKV = (size_t)B_ * SQ_ * D_;           // elements per tensor
  const size_t NW  = (size_t)B_ * SQ_ * SK_;          // weight elements
  ushort_t* Qb = (ushort_t*)d_ws;
  ushort_t* Kb = Qb + QKV;
  ushort_t* VT = Kb + QKV;

  const size_t need_bf16 = (3 * QKV + NW) * sizeof(ushort_t)
                         + (size_t)(2 * B_ * SQ_ + B_ * SK_) * sizeof(float);
  const bool use_bf16 = ws_size >= need_bf16;

  ushort_t* Eb = VT + QKV;                            // bf16 path only
  float* fbase = use_bf16 ? (float*)(Eb + NW) : (float*)(VT + QKV);
  float* q2     = fbase;
  float* k2     = q2 + B_ * SQ_;
  float* rowsum = k2 + B_ * SK_;

  hipMemsetAsync(rowsum, 0, (size_t)B_ * SQ_ * sizeof(float), stream);

  prep_qk<<<dim3(B_ * SQ_), 256, 0, stream>>>(Q, K, Qb, Kb, q2, k2);
  prep_vt<<<dim3(SK_ / 64, D_ / 64, B_), 256, 0, stream>>>(V, VT);

  if (use_bf16) {
    qk_kernel<1><<<dim3(SK_ / 128, SQ_ / 128, B_), 256, 0, stream>>>(
        Qb, Kb, q2, k2, alpha, nullptr, Eb, rowsum);
    pv_bf16<<<dim3(D_ / 128, SQ_ / 128, B_), 256, 0, stream>>>(Eb, VT, rowsum, out, W);
  } else {
    qk_kernel<0><<<dim3(SK_ / 128, SQ_ / 128, B_), 256, 0, stream>>>(
        Qb, Kb, q2, k2, alpha, W, nullptr, rowsum);
    pv_f32<<<dim3(D_ / 128, SQ_ / 128, B_), 256, 0, stream>>>(W, VT, rowsum, out);
    norm_f32<<<dim3(4096), 256, 0, stream>>>(W, rowsum);
  }
}

// Round 6
// 335.029 us; speedup vs baseline: 1.4324x; 1.0565x over previous
//
#include <hip/hip_runtime.h>
#include <stdint.h>

#define B_  8
#define SQ_ 2048
#define SK_ 2048
#define D_  512

typedef unsigned short ushort_t;
typedef __attribute__((ext_vector_type(8))) short          short8;
typedef __attribute__((ext_vector_type(8))) unsigned short ushort8;
typedef __attribute__((ext_vector_type(4))) float          f32x4;

__device__ __forceinline__ unsigned short f2bf(float x) {
  union { float f; unsigned u; } v; v.f = x;
  unsigned r = v.u + 0x7FFFu + ((v.u >> 16) & 1u);   // RNE, finite inputs only
  return (unsigned short)(r >> 16);
}

// async global->LDS, 16B per lane. LDS dest is wave-uniform base + lane*16.
__device__ __forceinline__ void gload_lds16(const void* g, void* l) {
  __builtin_amdgcn_global_load_lds(
      (__attribute__((address_space(1))) void*)(uintptr_t)g,
      (__attribute__((address_space(3))) void*)l, 16, 0, 0);
}

// ---------------- prep: Q,K f32 -> bf16 + row sum-of-squares ----------------
__global__ void prep_qk(const float* __restrict__ Q, const float* __restrict__ K,
                        ushort_t* __restrict__ Qb, ushort_t* __restrict__ Kb,
                        float* __restrict__ q2, float* __restrict__ k2) {
  const int t = threadIdx.x;
  const int rloc = t >> 7;                 // 0/1: which of the 2 rows
  const int row  = blockIdx.x * 2 + rloc;  // 0..32767 (Q rows then K rows)
  const bool isK = row >= B_ * SQ_;
  const int r = isK ? row - B_ * SQ_ : row;
  const float*    src = (isK ? K : Q) + (size_t)r * D_;
  ushort_t*       dst = (isK ? Kb : Qb) + (size_t)r * D_;
  float*          d2  = isK ? k2 : q2;

  const int c = (t & 127) * 4;
  float4 v = *(const float4*)(src + c);
  ushort4 o;
  o.x = f2bf(v.x); o.y = f2bf(v.y); o.z = f2bf(v.z); o.w = f2bf(v.w);
  *(ushort4*)(dst + c) = o;

  float s = v.x * v.x + v.y * v.y + v.z * v.z + v.w * v.w;
  for (int off = 32; off; off >>= 1) s += __shfl_down(s, off);
  __shared__ float ps[4];
  if ((t & 63) == 0) ps[t >> 6] = s;
  __syncthreads();
  if ((t & 127) == 0) d2[r] = ps[rloc * 2] + ps[rloc * 2 + 1];
}

// ---------------- prep: V [B][SK][D] f32 -> VT [B][D][SK] bf16 ----------------
__global__ void prep_vt(const float* __restrict__ V, ushort_t* __restrict__ VT) {
  const int b  = blockIdx.z;
  const int k0 = blockIdx.x * 64;
  const int d0 = blockIdx.y * 64;
  __shared__ __align__(16) ushort_t tile[64][68];
  const int t = threadIdx.x;
  const float* src = V + (size_t)b * SK_ * D_;
  #pragma unroll
  for (int i = 0; i < 4; ++i) {
    int kl = (t >> 4) + i * 16;
    int dl = (t & 15) * 4;
    float4 v = *(const float4*)(src + (size_t)(k0 + kl) * D_ + d0 + dl);
    tile[kl][dl]     = f2bf(v.x);
    tile[kl][dl + 1] = f2bf(v.y);
    tile[kl][dl + 2] = f2bf(v.z);
    tile[kl][dl + 3] = f2bf(v.w);
  }
  __syncthreads();
  ushort_t* dstb = VT + (size_t)b * D_ * SK_;
  #pragma unroll
  for (int j = 0; j < 2; ++j) {
    int chunk = t + j * 256;
    int dl = chunk >> 3;
    int kc = (chunk & 7) << 3;
    ushort8 o;
    #pragma unroll
    for (int m = 0; m < 8; ++m) o[m] = tile[kc + m][dl];
    *(ushort8*)(dstb + (size_t)(d0 + dl) * SK_ + k0 + kc) = o;
  }
}

// ---------------- QK^T + gaussian-kernel epilogue ----------------
// Swapped MFMA operands: acc[ki][qi] has row(reg)=K index, col(lane&15)=Q row,
// so each lane holds 4 CONSECUTIVE k columns -> 8B packed E stores.
// BF16E=1: store unnormalized numerators E as bf16 into ws.
// BF16E=0: store f32 into W region of d_out (fallback, small ws).
template <int BF16E>
__global__ __launch_bounds__(256) void qk_kernel(
    const ushort_t* __restrict__ Qb, const ushort_t* __restrict__ Kb,
    const float* __restrict__ q2, const float* __restrict__ k2,
    const float* __restrict__ alphap,
    float* __restrict__ Wf, ushort_t* __restrict__ Ebf,
    float* __restrict__ rowsum) {
  __shared__ __align__(16) ushort_t As[2][8192];  // Q tile dbuf 128x64 (swizzled)
  __shared__ __align__(16) ushort_t Bs[2][8192];  // K tile dbuf
  __shared__ float q2s[128], k2s[128];

  const int t = threadIdx.x;
  const int lane = t & 63, wid = t >> 6;
  const int wA = wid >> 1, wB = wid & 1;   // wA: k-half, wB: q-half

  // XCD-aware bijective swizzle: 2048 blocks, chunk 256 -> XCD x owns batch x.
  const int id  = blockIdx.x + 16 * blockIdx.y + 256 * blockIdx.z;
  const int swz = (id & 7) * 256 + (id >> 3);
  const int bx = swz & 15, by = (swz >> 4) & 15, bz = swz >> 8;

  const ushort_t* Aq = Qb + ((size_t)bz * SQ_ + by * 128) * D_;
  const ushort_t* Bk = Kb + ((size_t)bz * SK_ + bx * 128) * D_;

  if (t < 128) q2s[t] = q2[bz * SQ_ + by * 128 + t];
  else         k2s[t - 128] = k2[bz * SK_ + bx * 128 + (t - 128)];

  #define QK_STAGE(buf, kt)                                                     \
    _Pragma("unroll")                                                           \
    for (int i = 0; i < 4; ++i) {                                               \
      int s = t + i * 256;                                                      \
      int row = s >> 3;                                                         \
      int c16 = (s & 7) ^ (row & 7);                                            \
      gload_lds16(Aq + (size_t)row * D_ + (kt) * 64 + c16 * 8,                  \
                  (char*)As[buf] + s * 16);                                     \
      gload_lds16(Bk + (size_t)row * D_ + (kt) * 64 + c16 * 8,                  \
                  (char*)Bs[buf] + s * 16);                                     \
    }

  QK_STAGE(0, 0);
  __syncthreads();

  f32x4 acc[4][4] = {};
  #pragma unroll
  for (int kt = 0; kt < 8; ++kt) {
    const int cur = kt & 1;
    if (kt < 7) { QK_STAGE(cur ^ 1, kt + 1); }
    #pragma unroll
    for (int kk = 0; kk < 2; ++kk) {
      short8 qf[4], kf[4];
      #pragma unroll
      for (int qi = 0; qi < 4; ++qi) {
        int row = (wB << 6) + (qi << 4) + (lane & 15);
        int c = ((kk << 2) + (lane >> 4)) ^ (row & 7);
        qf[qi] = *(const short8*)((const char*)As[cur] + row * 128 + c * 16);
      }
      #pragma unroll
      for (int ki = 0; ki < 4; ++ki) {
        int row = (wA << 6) + (ki << 4) + (lane & 15);
        int c = ((kk << 2) + (lane >> 4)) ^ (row & 7);
        kf[ki] = *(const short8*)((const char*)Bs[cur] + row * 128 + c * 16);
      }
      #pragma unroll
      for (int ki = 0; ki < 4; ++ki)
        #pragma unroll
        for (int qi = 0; qi < 4; ++qi)
          acc[ki][qi] = __builtin_amdgcn_mfma_f32_16x16x32_bf16(kf[ki], qf[qi], acc[ki][qi], 0, 0, 0);
    }
    __syncthreads();   // drains vmcnt for next tile + protects buffer reuse
  }
  #undef QK_STAGE

  const float alpha = *alphap;
  const int r0 = (lane >> 4) << 2;   // k offset within frag
  const int cl = lane & 15;          // q row within frag

  float q2v[4];
  #pragma unroll
  for (int qi = 0; qi < 4; ++qi) q2v[qi] = q2s[(wB << 6) + (qi << 4) + cl];

  float se[4] = {0.f, 0.f, 0.f, 0.f};

  #pragma unroll
  for (int ki = 0; ki < 4; ++ki) {
    float k2v[4];
    #pragma unroll
    for (int r = 0; r < 4; ++r) k2v[r] = k2s[(wA << 6) + (ki << 4) + r0 + r];
    #pragma unroll
    for (int qi = 0; qi < 4; ++qi) {
      float x[4], e[4];
      #pragma unroll
      for (int r = 0; r < 4; ++r) {
        float sq = fmaxf(q2v[qi] + k2v[r] - 2.0f * acc[ki][qi][r], 0.0f);
        x[r] = -alpha * sq;
      }
      // exp(exp(x)) == 1.0f exactly when x < -20 (kv < 2e-9; 1+kv rounds to 1).
      int small = (x[0] < -20.f) & (x[1] < -20.f) & (x[2] < -20.f) & (x[3] < -20.f);
      if (__all(small)) {
        e[0] = e[1] = e[2] = e[3] = 1.0f;
      } else {
        #pragma unroll
        for (int r = 0; r < 4; ++r) e[r] = __expf(__expf(x[r]));
      }
      se[qi] += e[0] + e[1] + e[2] + e[3];

      const int qrow = (wB << 6) + (qi << 4) + cl;
      const int kcol = bx * 128 + (wA << 6) + (ki << 4) + r0;
      const size_t base = ((size_t)bz * SQ_ + by * 128 + qrow) * SK_ + kcol;
      if (BF16E) {
        unsigned long long pk =
            (unsigned long long)f2bf(e[0])
          | ((unsigned long long)f2bf(e[1]) << 16)
          | ((unsigned long long)f2bf(e[2]) << 32)
          | ((unsigned long long)f2bf(e[3]) << 48);
        *(unsigned long long*)(Ebf + base) = pk;
      } else {
        f32x4 w4 = {e[0], e[1], e[2], e[3]};
        __builtin_nontemporal_store(w4, (f32x4*)(Wf + base));
      }
    }
  }
  #pragma unroll
  for (int qi = 0; qi < 4; ++qi) {
    float s = se[qi];
    s += __shfl_xor(s, 16);
    s += __shfl_xor(s, 32);
    if (lane < 16)
      atomicAdd(&rowsum[bz * SQ_ + by * 128 + (wB << 6) + (qi << 4) + cl], s);
  }
}

// ---------------- PV (bf16): out = E*VT/rowsum, W written from E tiles ----------------
// Swapped MFMA: acc[di][qi] row(reg)=d index, col(lane&15)=q row -> float4 Out stores.
__global__ __launch_bounds__(256) void pv_bf16(
    const ushort_t* __restrict__ Eb, const ushort_t* __restrict__ VT,
    const float* __restrict__ rowsum, float* __restrict__ Out,
    float* __restrict__ W) {
  __shared__ __align__(16) ushort_t As[2][8192];  // E tile dbuf (swizzled)
  __shared__ __align__(16) ushort_t Bs[2][8192];  // VT tile dbuf (swizzled)
  __shared__ float rss[128];

  const int t = threadIdx.x;
  const int lane = t & 63, wid = t >> 6;
  const int wA = wid >> 1, wB = wid & 1;   // wA: d-half, wB: q-half

  // XCD swizzle: 512 blocks, chunk 64 -> XCD x owns batch x.
  const int id  = blockIdx.x + 4 * blockIdx.y + 64 * blockIdx.z;
  const int swz = (id & 7) * 64 + (id >> 3);
  const int bx = swz & 3, by = (swz >> 2) & 15, bz = swz >> 6;

  const ushort_t* Ebb = Eb + ((size_t)bz * SQ_ + by * 128) * SK_;
  const ushort_t* Vb  = VT + ((size_t)bz * D_ + bx * 128) * SK_;
  float* Wb = W + ((size_t)bz * SQ_ + by * 128) * SK_;

  if (t < 128) rss[t] = rowsum[bz * SQ_ + by * 128 + t];
  __syncthreads();                       // rss visible before W-write uses it

  #define PV_STAGE(buf, kt)                                                     \
    _Pragma("unroll")                                                           \
    for (int i = 0; i < 4; ++i) {                                               \
      int s = t + i * 256;                                                      \
      int row = s >> 3;                                                         \
      int c16 = (s & 7) ^ (row & 7);                                            \
      gload_lds16(Ebb + (size_t)row * SK_ + (kt) * 64 + c16 * 8,                \
                  (char*)As[buf] + s * 16);                                     \
      gload_lds16(Vb  + (size_t)row * SK_ + (kt) * 64 + c16 * 8,                \
                  (char*)Bs[buf] + s * 16);                                     \
    }

  PV_STAGE(0, 0);
  __syncthreads();

  const int wlo = bx * 8, whi = wlo + 8;   // this block's W kt-slice
  f32x4 acc[4][4] = {};
  for (int kt = 0; kt < 32; ++kt) {
    const int cur = kt & 1;
    if (kt < 31) { PV_STAGE(cur ^ 1, kt + 1); }

    #pragma unroll
    for (int kk = 0; kk < 2; ++kk) {
      short8 ef[4], vf[4];
      #pragma unroll
      for (int qi = 0; qi < 4; ++qi) {
        int row = (wB << 6) + (qi << 4) + (lane & 15);
        int c = ((kk << 2) + (lane >> 4)) ^ (row & 7);
        ef[qi] = *(const short8*)((const char*)As[cur] + row * 128 + c * 16);
      }
      #pragma unroll
      for (int di = 0; di < 4; ++di) {
        int row = (wA << 6) + (di << 4) + (lane & 15);
        int c = ((kk << 2) + (lane >> 4)) ^ (row & 7);
        vf[di] = *(const short8*)((const char*)Bs[cur] + row * 128 + c * 16);
      }
      #pragma unroll
      for (int di = 0; di < 4; ++di)
        #pragma unroll
        for (int qi = 0; qi < 4; ++qi)
          acc[di][qi] = __builtin_amdgcn_mfma_f32_16x16x32_bf16(vf[di], ef[qi], acc[di][qi], 0, 0, 0);
    }

    // write W f32 = E*rinv for this kt-slice straight from the staged tile
    // (after MFMA so stores overlap the matrix pipe; As[cur] valid until barrier)
    if (kt >= wlo && kt < whi) {
      #pragma unroll
      for (int i = 0; i < 4; ++i) {
        int s = t + i * 256;
        int row = s >> 3;
        int c16 = s & 7;
        int c16s = c16 ^ (row & 7);
        ushort8 ev = *(const ushort8*)((const char*)As[cur] + row * 128 + c16s * 16);
        float rinv = 1.0f / rss[row];
        f32x4 lo, hi;
        lo.x = __uint_as_float((unsigned)ev[0] << 16) * rinv;
        lo.y = __uint_as_float((unsigned)ev[1] << 16) * rinv;
        lo.z = __uint_as_float((unsigned)ev[2] << 16) * rinv;
        lo.w = __uint_as_float((unsigned)ev[3] << 16) * rinv;
        hi.x = __uint_as_float((unsigned)ev[4] << 16) * rinv;
        hi.y = __uint_as_float((unsigned)ev[5] << 16) * rinv;
        hi.z = __uint_as_float((unsigned)ev[6] << 16) * rinv;
        hi.w = __uint_as_float((unsigned)ev[7] << 16) * rinv;
        float* wp = Wb + (size_t)row * SK_ + kt * 64 + c16 * 8;
        __builtin_nontemporal_store(lo, (f32x4*)wp);
        __builtin_nontemporal_store(hi, (f32x4*)(wp + 4));
      }
    }
    __syncthreads();
  }
  #undef PV_STAGE

  float* Ob = Out + ((size_t)bz * SQ_ + by * 128) * D_ + bx * 128;
  const int r0 = (lane >> 4) << 2;
  const int cl = lane & 15;
  #pragma unroll
  for (int di = 0; di < 4; ++di) {
    #pragma unroll
    for (int qi = 0; qi < 4; ++qi) {
      int qrow = (wB << 6) + (qi << 4) + cl;
      int dcol = (wA << 6) + (di << 4) + r0;
      float rinv = 1.0f / rss[qrow];
      f32x4 o;
      o.x = acc[di][qi][0] * rinv;
      o.y = acc[di][qi][1] * rinv;
      o.z = acc[di][qi][2] * rinv;
      o.w = acc[di][qi][3] * rinv;
      __builtin_nontemporal_store(o, (f32x4*)(Ob + (size_t)qrow * D_ + dcol));
    }
  }
}

// ---------------- PV (f32 fallback): out = E_f32 * VT / rowsum ----------------
__global__ __launch_bounds__(256) void pv_f32(
    const float* __restrict__ E, const ushort_t* __restrict__ VT,
    const float* __restrict__ rowsum, float* __restrict__ Out) {
  __shared__ __align__(16) ushort_t As[8192];
  __shared__ __align__(16) ushort_t Bs[8192];
  __shared__ float rss[128];

  const int t = threadIdx.x;
  const int lane = t & 63, wid = t >> 6;
  const int wm = wid >> 1, wn = wid & 1;
  const int bx = blockIdx.x, by = blockIdx.y, bz = blockIdx.z;

  const float*    Eb = E + ((size_t)bz * SQ_ + by * 128) * SK_;
  const ushort_t* Vb = VT + ((size_t)bz * D_ + bx * 128) * SK_;

  if (t < 128) rss[t] = rowsum[bz * SQ_ + by * 128 + t];

  f32x4 acc[4][4] = {};
  for (int kt = 0; kt < SK_ / 64; ++kt) {
    float4 va[4][2];
    #pragma unroll
    for (int i = 0; i < 4; ++i) {
      int s = t + i * 256;
      int row = s >> 3, c16 = s & 7;
      const float* g = Eb + (size_t)row * SK_ + kt * 64 + c16 * 8;
      va[i][0] = *(const float4*)g;
      va[i][1] = *(const float4*)(g + 4);
    }
    __syncthreads();
    #pragma unroll
    for (int i = 0; i < 4; ++i) {
      int s = t + i * 256;
      int row = s >> 3, c16 = s & 7;
      int c16s = c16 ^ (row & 7);
      ushort8 o;
      o[0] = f2bf(va[i][0].x); o[1] = f2bf(va[i][0].y);
      o[2] = f2bf(va[i][0].z); o[3] = f2bf(va[i][0].w);
      o[4] = f2bf(va[i][1].x); o[5] = f2bf(va[i][1].y);
      o[6] = f2bf(va[i][1].z); o[7] = f2bf(va[i][1].w);
      *(ushort8*)((char*)As + row * 128 + c16s * 16) = o;
      gload_lds16(Vb + (size_t)row * SK_ + kt * 64 + c16s * 8, (char*)Bs + s * 16);
    }
    __syncthreads();
    #pragma unroll
    for (int kk = 0; kk < 2; ++kk) {
      short8 a[4], bf[4];
      #pragma unroll
      for (int mi = 0; mi < 4; ++mi) {
        int row = (wm << 6) + (mi << 4) + (lane & 15);
        int c = ((kk << 2) + (lane >> 4)) ^ (row & 7);
        a[mi] = *(const short8*)((const char*)As + row * 128 + c * 16);
      }
      #pragma unroll
      for (int ni = 0; ni < 4; ++ni) {
        int col = (wn << 6) + (ni << 4) + (lane & 15);
        int c = ((kk << 2) + (lane >> 4)) ^ (col & 7);
        bf[ni] = *(const short8*)((const char*)Bs + col * 128 + c * 16);
      }
      #pragma unroll
      for (int mi = 0; mi < 4; ++mi)
        #pragma unroll
        for (int ni = 0; ni < 4; ++ni)
          acc[mi][ni] = __builtin_amdgcn_mfma_f32_16x16x32_bf16(a[mi], bf[ni], acc[mi][ni], 0, 0, 0);
    }
  }

  float* Ob = Out + ((size_t)bz * SQ_ + by * 128) * D_ + bx * 128;
  const int r0 = (lane >> 4) << 2;
  const int cl = lane & 15;
  #pragma unroll
  for (int mi = 0; mi < 4; ++mi) {
    #pragma unroll
    for (int r = 0; r < 4; ++r) {
      int rl = (wm << 6) + (mi << 4) + r0 + r;
      float rinv = 1.0f / rss[rl];
      #pragma unroll
      for (int ni = 0; ni < 4; ++ni)
        Ob[(size_t)rl * D_ + (wn << 6) + (ni << 4) + cl] = acc[mi][ni][r] * rinv;
    }
  }
}

// ---------------- normalize in place (f32 fallback) ----------------
__global__ void norm_f32(float* __restrict__ W, const float* __restrict__ rowsum) {
  const size_t total4 = (size_t)B_ * SQ_ * SK_ / 4;
  for (size_t i = (size_t)blockIdx.x * blockDim.x + threadIdx.x; i < total4;
       i += (size_t)gridDim.x * blockDim.x) {
    float4 v = ((const float4*)W)[i];
    float rinv = 1.0f / rowsum[i >> 9];    // 512 float4 per row
    v.x *= rinv; v.y *= rinv; v.z *= rinv; v.w *= rinv;
    ((float4*)W)[i] = v;
  }
}

extern "C" void kernel_launch(void* const* d_in, const int* in_sizes, int n_in,
                              void* d_out, int out_size, void* d_ws, size_t ws_size,
                              hipStream_t stream) {
  const float* Q     = (const float*)d_in[0];
  const float* K     = (const float*)d_in[1];
  const float* V     = (const float*)d_in[2];
  const float* alpha = (const float*)d_in[3];

  float* out = (float*)d_out;                         // [B][SQ][D]
  float* W   = out + (size_t)B_ * SQ_ * D_;           // [B][SQ][SK]

  const size_t QKV = (size_t)B_ * SQ_ * D_;           // elements per tensor
  const size_t NW  = (size_t)B_ * SQ_ * SK_;          // weight elements
  ushort_t* Qb = (ushort_t*)d_ws;
  ushort_t* Kb = Qb + QKV;
  ushort_t* VT = Kb + QKV;

  const size_t need_bf16 = (3 * QKV + NW) * sizeof(ushort_t)
                         + (size_t)(2 * B_ * SQ_ + B_ * SK_) * sizeof(float);
  const bool use_bf16 = ws_size >= need_bf16;

  ushort_t* Eb = VT + QKV;                            // bf16 path only
  float* fbase = use_bf16 ? (float*)(Eb + NW) : (float*)(VT + QKV);
  float* q2     = fbase;
  float* k2     = q2 + B_ * SQ_;
  float* rowsum = k2 + B_ * SK_;

  hipMemsetAsync(rowsum, 0, (size_t)B_ * SQ_ * sizeof(float), stream);

  prep_qk<<<dim3(B_ * SQ_), 256, 0, stream>>>(Q, K, Qb, Kb, q2, k2);
  prep_vt<<<dim3(SK_ / 64, D_ / 64, B_), 256, 0, stream>>>(V, VT);

  if (use_bf16) {
    qk_kernel<1><<<dim3(SK_ / 128, SQ_ / 128, B_), 256, 0, stream>>>(
        Qb, Kb, q2, k2, alpha, nullptr, Eb, rowsum);
    pv_bf16<<<dim3(D_ / 128, SQ_ / 128, B_), 256, 0, stream>>>(Eb, VT, rowsum, out, W);
  } else {
    qk_kernel<0><<<dim3(SK_ / 128, SQ_ / 128, B_), 256, 0, stream>>>(
        Qb, Kb, q2, k2, alpha, W, nullptr, rowsum);
    pv_f32<<<dim3(D_ / 128, SQ_ / 128, B_), 256, 0, stream>>>(W, VT, rowsum, out);
    norm_f32<<<dim3(4096), 256, 0, stream>>>(W, rowsum);
  }
}